// Round 1
// baseline (550.155 us; speedup 1.0000x reference)
//
#include <hip/hip_runtime.h>
#include <hip/hip_bf16.h>
#include <math.h>

// Problem constants
#define B_ 4
#define L_ 1024
#define DI 2048
#define DS 16
#define RR 128          // DT_RANK
#define KXZ 160         // DT_RANK + 2*DS
#define NC 16           // chunks along L
#define LC 64           // chunk length
#define NROW (B_*L_)    // 4096

// ---------------------------------------------------------------------------
// K1: xz[m][k] = sum_d x[m][d] * W_x[k][d]   (m=4096 rows, k=160, K=2048)
// block = 256 threads, computes 16 rows x 160 cols
// ---------------------------------------------------------------------------
__global__ __launch_bounds__(256) void k_gemm_xz(const float* __restrict__ x,
                                                 const float* __restrict__ Wx,
                                                 float* __restrict__ xz) {
    __shared__ float xs[16][65];     // 16 rows x 64 k, +1 pad
    __shared__ float wt[64][161];    // 64 k x 160 cols, +1 pad
    const int row0 = blockIdx.x * 16;
    const int tid = threadIdx.x;
    float acc[16];
#pragma unroll
    for (int r = 0; r < 16; ++r) acc[r] = 0.f;

    for (int k0 = 0; k0 < DI; k0 += 64) {
        for (int idx = tid; idx < 16 * 64; idx += 256) {
            int r = idx >> 6, kk = idx & 63;
            xs[r][kk] = x[(size_t)(row0 + r) * DI + k0 + kk];
        }
        for (int idx = tid; idx < 160 * 64; idx += 256) {
            int c = idx >> 6, kk = idx & 63;
            wt[kk][c] = Wx[(size_t)c * DI + k0 + kk];
        }
        __syncthreads();
        if (tid < 160) {
            for (int kk = 0; kk < 64; ++kk) {
                float wv = wt[kk][tid];
#pragma unroll
                for (int r = 0; r < 16; ++r) acc[r] += xs[r][kk] * wv;
            }
        }
        __syncthreads();
    }
    if (tid < 160) {
#pragma unroll
        for (int r = 0; r < 16; ++r)
            xz[(size_t)(row0 + r) * KXZ + tid] = acc[r];
    }
}

// ---------------------------------------------------------------------------
// K2: dt[m][d] = softplus( sum_r xz[m][r] * W_dt[d][r] + b_dt[d] )
// block = 256 threads, tile 32 rows x 64 cols, K=128
// grid = 128 row-groups * 32 col-groups = 4096 blocks
// ---------------------------------------------------------------------------
__global__ __launch_bounds__(256) void k_gemm_dt(const float* __restrict__ xz,
                                                 const float* __restrict__ Wdt,
                                                 const float* __restrict__ bdt,
                                                 float* __restrict__ dt) {
    __shared__ float rs[32][129];
    __shared__ float wt[128][65];
    const int m0 = (blockIdx.x & 127) * 32;
    const int d0 = (blockIdx.x >> 7) * 64;
    const int tid = threadIdx.x;

    for (int idx = tid; idx < 32 * 128; idx += 256) {
        int r = idx >> 7, k = idx & 127;
        rs[r][k] = xz[(size_t)(m0 + r) * KXZ + k];
    }
    for (int idx = tid; idx < 64 * 128; idx += 256) {
        int c = idx >> 7, k = idx & 127;
        wt[k][c] = Wdt[(size_t)(d0 + c) * RR + k];
    }
    __syncthreads();

    const int c = tid & 63;
    const int rg = tid >> 6;            // 0..3 -> rows rg*8 .. rg*8+7
    float acc[8];
#pragma unroll
    for (int j = 0; j < 8; ++j) acc[j] = 0.f;
    for (int k = 0; k < 128; ++k) {
        float wv = wt[k][c];
#pragma unroll
        for (int j = 0; j < 8; ++j) acc[j] += rs[rg * 8 + j][k] * wv;
    }
    const float bb = bdt[d0 + c];
#pragma unroll
    for (int j = 0; j < 8; ++j) {
        float z = acc[j] + bb;
        float sp = fmaxf(z, 0.f) + log1pf(__expf(-fabsf(z)));
        dt[(size_t)(m0 + rg * 8 + j) * DI + d0 + c] = sp;
    }
}

// ---------------------------------------------------------------------------
// K3 (phase A): per (b, chunk, d): local zero-init scan over the chunk.
// Emits S = sum(dt) over chunk and the chunk-final local state LE[16].
// grid = B * NC * (DI/256) = 4*16*8 = 512 blocks, 256 threads
// ---------------------------------------------------------------------------
__global__ __launch_bounds__(256) void k_scan_a(const float* __restrict__ dt,
                                                const float* __restrict__ x,
                                                const float* __restrict__ xz,
                                                const float* __restrict__ A_log,
                                                float* __restrict__ Sws,
                                                float* __restrict__ LE) {
    const int bc = blockIdx.x;
    const int dg = bc & 7;
    const int c  = (bc >> 3) & 15;
    const int b  = bc >> 7;
    const int d  = dg * 256 + threadIdx.x;

    __shared__ float bs[LC * DS];
    for (int idx = threadIdx.x; idx < LC * DS; idx += 256) {
        int l = idx >> 4, n = idx & 15;
        bs[idx] = xz[((size_t)(b * L_ + c * LC + l)) * KXZ + RR + n];
    }
    float a[16];
#pragma unroll
    for (int n = 0; n < 16; ++n) a[n] = -__expf(A_log[(size_t)d * DS + n]);
    __syncthreads();

    float h[16];
#pragma unroll
    for (int n = 0; n < 16; ++n) h[n] = 0.f;
    float S = 0.f;
    const size_t base = ((size_t)b * L_ + c * LC) * DI + d;
    for (int l = 0; l < LC; ++l) {
        float dt_v = dt[base + (size_t)l * DI];
        float x_v  = x[base + (size_t)l * DI];
        S += dt_v;
        float dx = dt_v * x_v;
#pragma unroll
        for (int n = 0; n < 16; ++n)
            h[n] = __expf(dt_v * a[n]) * h[n] + dx * bs[l * 16 + n];
    }
    Sws[((size_t)b * NC + c) * DI + d] = S;
    const size_t leb = ((size_t)(b * NC + c) * DS) * DI + d;
#pragma unroll
    for (int n = 0; n < 16; ++n) LE[leb + (size_t)n * DI] = h[n];
}

// ---------------------------------------------------------------------------
// K4 (phase B): per (b,d): combine the 16 chunks sequentially; store the
// state ENTERING each chunk: H0[c] ; h <- exp(a*S_c)*h + LE_c
// grid = 32 blocks x 256
// ---------------------------------------------------------------------------
__global__ __launch_bounds__(256) void k_scan_b(const float* __restrict__ A_log,
                                                const float* __restrict__ Sws,
                                                const float* __restrict__ LE,
                                                float* __restrict__ H0) {
    const int idx = blockIdx.x * 256 + threadIdx.x;   // 0..8191
    const int d = idx & (DI - 1);
    const int b = idx >> 11;
    float a[16];
#pragma unroll
    for (int n = 0; n < 16; ++n) a[n] = -__expf(A_log[(size_t)d * DS + n]);
    float h[16];
#pragma unroll
    for (int n = 0; n < 16; ++n) h[n] = 0.f;
    for (int c = 0; c < NC; ++c) {
        const size_t hb = ((size_t)(b * NC + c) * DS) * DI + d;
#pragma unroll
        for (int n = 0; n < 16; ++n) H0[hb + (size_t)n * DI] = h[n];
        float S = Sws[((size_t)b * NC + c) * DI + d];
#pragma unroll
        for (int n = 0; n < 16; ++n)
            h[n] = __expf(a[n] * S) * h[n] + LE[hb + (size_t)n * DI];
    }
}

// ---------------------------------------------------------------------------
// K5 (phase C): full scan per chunk with correct initial state; fused
// y = c . h  and  out = y + x*D epilogue.
// grid = 512 blocks, 256 threads (same decode as K3)
// ---------------------------------------------------------------------------
__global__ __launch_bounds__(256) void k_scan_c(const float* __restrict__ dt,
                                                const float* __restrict__ x,
                                                const float* __restrict__ xz,
                                                const float* __restrict__ A_log,
                                                const float* __restrict__ H0,
                                                const float* __restrict__ Dp,
                                                float* __restrict__ out) {
    const int bc = blockIdx.x;
    const int dg = bc & 7;
    const int c  = (bc >> 3) & 15;
    const int b  = bc >> 7;
    const int d  = dg * 256 + threadIdx.x;

    __shared__ float bs[LC * DS];
    __shared__ float cs[LC * DS];
    for (int idx = threadIdx.x; idx < LC * DS; idx += 256) {
        int l = idx >> 4, n = idx & 15;
        const size_t rowb = ((size_t)(b * L_ + c * LC + l)) * KXZ;
        bs[idx] = xz[rowb + RR + n];
        cs[idx] = xz[rowb + RR + DS + n];
    }
    float a[16];
#pragma unroll
    for (int n = 0; n < 16; ++n) a[n] = -__expf(A_log[(size_t)d * DS + n]);
    float h[16];
    const size_t hb = ((size_t)(b * NC + c) * DS) * DI + d;
#pragma unroll
    for (int n = 0; n < 16; ++n) h[n] = H0[hb + (size_t)n * DI];
    const float Dv = Dp[d];
    __syncthreads();

    const size_t base = ((size_t)b * L_ + c * LC) * DI + d;
    for (int l = 0; l < LC; ++l) {
        float dt_v = dt[base + (size_t)l * DI];
        float x_v  = x[base + (size_t)l * DI];
        float dx = dt_v * x_v;
        float y = 0.f;
#pragma unroll
        for (int n = 0; n < 16; ++n) {
            h[n] = __expf(dt_v * a[n]) * h[n] + dx * bs[l * 16 + n];
            y += cs[l * 16 + n] * h[n];
        }
        out[base + (size_t)l * DI] = y + x_v * Dv;
    }
}

// ---------------------------------------------------------------------------
extern "C" void kernel_launch(void* const* d_in, const int* in_sizes, int n_in,
                              void* d_out, int out_size, void* d_ws, size_t ws_size,
                              hipStream_t stream) {
    const float* x     = (const float*)d_in[0];
    const float* Wx    = (const float*)d_in[1];
    const float* Wdt   = (const float*)d_in[2];
    const float* bdt   = (const float*)d_in[3];
    const float* A_log = (const float*)d_in[4];
    const float* Dp    = (const float*)d_in[5];
    float* out = (float*)d_out;

    float* ws = (float*)d_ws;
    float* xz  = ws;                                    // 4096*160      = 655360
    float* dt  = xz + (size_t)NROW * KXZ;               // 4096*2048     = 8388608
    float* Sws = dt + (size_t)NROW * DI;                // 4*16*2048     = 131072
    float* LE  = Sws + (size_t)B_ * NC * DI;            // 4*16*16*2048  = 2097152
    float* H0  = LE + (size_t)B_ * NC * DS * DI;        // 4*16*16*2048  = 2097152

    k_gemm_xz<<<NROW / 16, 256, 0, stream>>>(x, Wx, xz);
    k_gemm_dt<<<(NROW / 32) * (DI / 64), 256, 0, stream>>>(xz, Wdt, bdt, dt);
    k_scan_a<<<B_ * NC * (DI / 256), 256, 0, stream>>>(dt, x, xz, A_log, Sws, LE);
    k_scan_b<<<B_ * DI / 256, 256, 0, stream>>>(A_log, Sws, LE, H0);
    k_scan_c<<<B_ * NC * (DI / 256), 256, 0, stream>>>(dt, x, xz, A_log, H0, Dp, out);
}

// Round 2
// 332.370 us; speedup vs baseline: 1.6552x; 1.6552x over previous
//
#include <hip/hip_runtime.h>
#include <hip/hip_bf16.h>
#include <math.h>

// Problem constants
#define B_ 4
#define L_ 1024
#define DI 2048
#define DS 16
#define RR 128          // DT_RANK
#define KXZ 160         // DT_RANK + 2*DS
#define NC 16           // chunks along L
#define LC 64           // chunk length
#define NROW (B_*L_)    // 4096

// ---------------------------------------------------------------------------
// K1: xz[m][k] = sum_d x[m][d] * W_x[k][d]   (M=4096, N=160, K=2048)
// K-split x8, 64-row x 160-col tile per block, 8x5 fp32 acc per thread,
// partials accumulated with atomicAdd (xz pre-zeroed).
// grid = (4096/64) * 8 = 512 blocks, 256 threads
// ---------------------------------------------------------------------------
#define TM 64
#define KS 8
#define KSEG (DI / KS)   // 256
#define KC 32            // k staged per iteration

__global__ __launch_bounds__(256) void k_gemm_xz(const float* __restrict__ x,
                                                 const float* __restrict__ Wx,
                                                 float* __restrict__ xz) {
    __shared__ float xs[TM][KC + 4];    // [row][k], pad 4 to keep 16B-aligned rows
    __shared__ float wt[KC][KXZ + 1];   // [k][col]
    const int rg = blockIdx.x & 63;
    const int ks = blockIdx.x >> 6;
    const int row0 = rg * TM;
    const int kbase = ks * KSEG;
    const int tid = threadIdx.x;
    const int tx = tid & 31;   // col:  c = tx + 32*j, j<5
    const int ty = tid >> 5;   // row:  r = ty + 8*i,  i<8

    float acc[8][5];
#pragma unroll
    for (int i = 0; i < 8; ++i)
#pragma unroll
        for (int j = 0; j < 5; ++j) acc[i][j] = 0.f;

    for (int kc = 0; kc < KSEG / KC; ++kc) {
        const int k0 = kbase + kc * KC;
        // stage x tile: 64 rows x 32 k  (512 float4 loads)
        for (int i = tid; i < TM * (KC / 4); i += 256) {
            int row = i >> 3, kq = i & 7;
            const float4 v = *(const float4*)&x[(size_t)(row0 + row) * DI + k0 + kq * 4];
            xs[row][kq * 4 + 0] = v.x;
            xs[row][kq * 4 + 1] = v.y;
            xs[row][kq * 4 + 2] = v.z;
            xs[row][kq * 4 + 3] = v.w;
        }
        // stage W tile (transposed): 160 cols x 32 k (1280 float4 loads)
        for (int i = tid; i < KXZ * (KC / 4); i += 256) {
            int c = i >> 3, kq = i & 7;
            const float4 v = *(const float4*)&Wx[(size_t)c * DI + k0 + kq * 4];
            wt[kq * 4 + 0][c] = v.x;
            wt[kq * 4 + 1][c] = v.y;
            wt[kq * 4 + 2][c] = v.z;
            wt[kq * 4 + 3][c] = v.w;
        }
        __syncthreads();
#pragma unroll 8
        for (int kk = 0; kk < KC; ++kk) {
            float wv[5], xv[8];
#pragma unroll
            for (int j = 0; j < 5; ++j) wv[j] = wt[kk][tx + 32 * j];
#pragma unroll
            for (int i = 0; i < 8; ++i) xv[i] = xs[ty + 8 * i][kk];
#pragma unroll
            for (int i = 0; i < 8; ++i)
#pragma unroll
                for (int j = 0; j < 5; ++j) acc[i][j] += xv[i] * wv[j];
        }
        __syncthreads();
    }
#pragma unroll
    for (int i = 0; i < 8; ++i)
#pragma unroll
        for (int j = 0; j < 5; ++j)
            atomicAdd(&xz[(size_t)(row0 + ty + 8 * i) * KXZ + tx + 32 * j], acc[i][j]);
}

// ---------------------------------------------------------------------------
// K2: dt[m][d] = softplus( sum_r xz[m][r] * W_dt[d][r] + b_dt[d] )
// block = 256 threads, tile 32 rows x 64 cols, K=128
// grid = 128 row-groups * 32 col-groups = 4096 blocks
// ---------------------------------------------------------------------------
__global__ __launch_bounds__(256) void k_gemm_dt(const float* __restrict__ xz,
                                                 const float* __restrict__ Wdt,
                                                 const float* __restrict__ bdt,
                                                 float* __restrict__ dt) {
    __shared__ float rs[32][129];
    __shared__ float wt[128][65];
    const int m0 = (blockIdx.x & 127) * 32;
    const int d0 = (blockIdx.x >> 7) * 64;
    const int tid = threadIdx.x;

    for (int idx = tid; idx < 32 * 128; idx += 256) {
        int r = idx >> 7, k = idx & 127;
        rs[r][k] = xz[(size_t)(m0 + r) * KXZ + k];
    }
    for (int idx = tid; idx < 64 * 128; idx += 256) {
        int c = idx >> 7, k = idx & 127;
        wt[k][c] = Wdt[(size_t)(d0 + c) * RR + k];
    }
    __syncthreads();

    const int c = tid & 63;
    const int rg = tid >> 6;            // 0..3 -> rows rg*8 .. rg*8+7
    float acc[8];
#pragma unroll
    for (int j = 0; j < 8; ++j) acc[j] = 0.f;
    for (int k = 0; k < 128; ++k) {
        float wv = wt[k][c];
#pragma unroll
        for (int j = 0; j < 8; ++j) acc[j] += rs[rg * 8 + j][k] * wv;
    }
    const float bb = bdt[d0 + c];
#pragma unroll
    for (int j = 0; j < 8; ++j) {
        float z = acc[j] + bb;
        float sp = fmaxf(z, 0.f) + log1pf(__expf(-fabsf(z)));
        dt[(size_t)(m0 + rg * 8 + j) * DI + d0 + c] = sp;
    }
}

// ---------------------------------------------------------------------------
// K3 (phase A): per (b, chunk, d): local zero-init scan over the chunk.
// Emits S = sum(dt) over chunk and the chunk-final local state LE[16].
// grid = B * NC * (DI/256) = 4*16*8 = 512 blocks, 256 threads
// ---------------------------------------------------------------------------
__global__ __launch_bounds__(256) void k_scan_a(const float* __restrict__ dt,
                                                const float* __restrict__ x,
                                                const float* __restrict__ xz,
                                                const float* __restrict__ A_log,
                                                float* __restrict__ Sws,
                                                float* __restrict__ LE) {
    const int bc = blockIdx.x;
    const int dg = bc & 7;
    const int c  = (bc >> 3) & 15;
    const int b  = bc >> 7;
    const int d  = dg * 256 + threadIdx.x;

    __shared__ float bs[LC * DS];
    for (int idx = threadIdx.x; idx < LC * DS; idx += 256) {
        int l = idx >> 4, n = idx & 15;
        bs[idx] = xz[((size_t)(b * L_ + c * LC + l)) * KXZ + RR + n];
    }
    float a[16];
#pragma unroll
    for (int n = 0; n < 16; ++n) a[n] = -__expf(A_log[(size_t)d * DS + n]);
    __syncthreads();

    float h[16];
#pragma unroll
    for (int n = 0; n < 16; ++n) h[n] = 0.f;
    float S = 0.f;
    const size_t base = ((size_t)b * L_ + c * LC) * DI + d;
    for (int l = 0; l < LC; ++l) {
        float dt_v = dt[base + (size_t)l * DI];
        float x_v  = x[base + (size_t)l * DI];
        S += dt_v;
        float dx = dt_v * x_v;
#pragma unroll
        for (int n = 0; n < 16; ++n)
            h[n] = __expf(dt_v * a[n]) * h[n] + dx * bs[l * 16 + n];
    }
    Sws[((size_t)b * NC + c) * DI + d] = S;
    const size_t leb = ((size_t)(b * NC + c) * DS) * DI + d;
#pragma unroll
    for (int n = 0; n < 16; ++n) LE[leb + (size_t)n * DI] = h[n];
}

// ---------------------------------------------------------------------------
// K4 (phase B): per (b,d): combine the 16 chunks sequentially; store the
// state ENTERING each chunk: H0[c] ; h <- exp(a*S_c)*h + LE_c
// grid = 32 blocks x 256
// ---------------------------------------------------------------------------
__global__ __launch_bounds__(256) void k_scan_b(const float* __restrict__ A_log,
                                                const float* __restrict__ Sws,
                                                const float* __restrict__ LE,
                                                float* __restrict__ H0) {
    const int idx = blockIdx.x * 256 + threadIdx.x;   // 0..8191
    const int d = idx & (DI - 1);
    const int b = idx >> 11;
    float a[16];
#pragma unroll
    for (int n = 0; n < 16; ++n) a[n] = -__expf(A_log[(size_t)d * DS + n]);
    float h[16];
#pragma unroll
    for (int n = 0; n < 16; ++n) h[n] = 0.f;
    for (int c = 0; c < NC; ++c) {
        const size_t hb = ((size_t)(b * NC + c) * DS) * DI + d;
#pragma unroll
        for (int n = 0; n < 16; ++n) H0[hb + (size_t)n * DI] = h[n];
        float S = Sws[((size_t)b * NC + c) * DI + d];
#pragma unroll
        for (int n = 0; n < 16; ++n)
            h[n] = __expf(a[n] * S) * h[n] + LE[hb + (size_t)n * DI];
    }
}

// ---------------------------------------------------------------------------
// K5 (phase C): full scan per chunk with correct initial state; fused
// y = c . h  and  out = y + x*D epilogue.
// grid = 512 blocks, 256 threads (same decode as K3)
// ---------------------------------------------------------------------------
__global__ __launch_bounds__(256) void k_scan_c(const float* __restrict__ dt,
                                                const float* __restrict__ x,
                                                const float* __restrict__ xz,
                                                const float* __restrict__ A_log,
                                                const float* __restrict__ H0,
                                                const float* __restrict__ Dp,
                                                float* __restrict__ out) {
    const int bc = blockIdx.x;
    const int dg = bc & 7;
    const int c  = (bc >> 3) & 15;
    const int b  = bc >> 7;
    const int d  = dg * 256 + threadIdx.x;

    __shared__ float bs[LC * DS];
    __shared__ float cs[LC * DS];
    for (int idx = threadIdx.x; idx < LC * DS; idx += 256) {
        int l = idx >> 4, n = idx & 15;
        const size_t rowb = ((size_t)(b * L_ + c * LC + l)) * KXZ;
        bs[idx] = xz[rowb + RR + n];
        cs[idx] = xz[rowb + RR + DS + n];
    }
    float a[16];
#pragma unroll
    for (int n = 0; n < 16; ++n) a[n] = -__expf(A_log[(size_t)d * DS + n]);
    float h[16];
    const size_t hb = ((size_t)(b * NC + c) * DS) * DI + d;
#pragma unroll
    for (int n = 0; n < 16; ++n) h[n] = H0[hb + (size_t)n * DI];
    const float Dv = Dp[d];
    __syncthreads();

    const size_t base = ((size_t)b * L_ + c * LC) * DI + d;
    for (int l = 0; l < LC; ++l) {
        float dt_v = dt[base + (size_t)l * DI];
        float x_v  = x[base + (size_t)l * DI];
        float dx = dt_v * x_v;
        float y = 0.f;
#pragma unroll
        for (int n = 0; n < 16; ++n) {
            h[n] = __expf(dt_v * a[n]) * h[n] + dx * bs[l * 16 + n];
            y += cs[l * 16 + n] * h[n];
        }
        out[base + (size_t)l * DI] = y + x_v * Dv;
    }
}

// ---------------------------------------------------------------------------
extern "C" void kernel_launch(void* const* d_in, const int* in_sizes, int n_in,
                              void* d_out, int out_size, void* d_ws, size_t ws_size,
                              hipStream_t stream) {
    const float* x     = (const float*)d_in[0];
    const float* Wx    = (const float*)d_in[1];
    const float* Wdt   = (const float*)d_in[2];
    const float* bdt   = (const float*)d_in[3];
    const float* A_log = (const float*)d_in[4];
    const float* Dp    = (const float*)d_in[5];
    float* out = (float*)d_out;

    float* ws = (float*)d_ws;
    float* xz  = ws;                                    // 4096*160      = 655360
    float* dt  = xz + (size_t)NROW * KXZ;               // 4096*2048     = 8388608
    float* Sws = dt + (size_t)NROW * DI;                // 4*16*2048     = 131072
    float* LE  = Sws + (size_t)B_ * NC * DI;            // 4*16*16*2048  = 2097152
    float* H0  = LE + (size_t)B_ * NC * DS * DI;        // 4*16*16*2048  = 2097152

    hipMemsetAsync(xz, 0, (size_t)NROW * KXZ * sizeof(float), stream);
    k_gemm_xz<<<(NROW / TM) * KS, 256, 0, stream>>>(x, Wx, xz);
    k_gemm_dt<<<(NROW / 32) * (DI / 64), 256, 0, stream>>>(xz, Wdt, bdt, dt);
    k_scan_a<<<B_ * NC * (DI / 256), 256, 0, stream>>>(dt, x, xz, A_log, Sws, LE);
    k_scan_b<<<B_ * DI / 256, 256, 0, stream>>>(A_log, Sws, LE, H0);
    k_scan_c<<<B_ * NC * (DI / 256), 256, 0, stream>>>(dt, x, xz, A_log, H0, Dp, out);
}

// Round 3
// 299.137 us; speedup vs baseline: 1.8391x; 1.1111x over previous
//
#include <hip/hip_runtime.h>
#include <hip/hip_bf16.h>
#include <math.h>

// Problem constants
#define B_ 4
#define L_ 1024
#define DI 2048
#define DS 16
#define RR 128          // DT_RANK
#define KXZ 160         // DT_RANK + 2*DS
#define NC 16           // chunks along L
#define LC 64           // chunk length
#define NROW (B_*L_)    // 4096

// ---------------------------------------------------------------------------
// K1: xz[m][k] = sum_d x[m][d] * W_x[k][d]   (M=4096, N=160, K=2048)
// K-split x8, 64-row x 160-col tile per block, 8x5 fp32 acc per thread,
// partials accumulated with atomicAdd (xz pre-zeroed).
// grid = (4096/64) * 8 = 512 blocks, 256 threads
// ---------------------------------------------------------------------------
#define TM 64
#define KS 8
#define KSEG (DI / KS)   // 256
#define KC 32            // k staged per iteration

__global__ __launch_bounds__(256) void k_gemm_xz(const float* __restrict__ x,
                                                 const float* __restrict__ Wx,
                                                 float* __restrict__ xz) {
    __shared__ float xs[TM][KC + 4];    // [row][k], pad 4 to keep 16B-aligned rows
    __shared__ float wt[KC][KXZ + 1];   // [k][col]
    const int rg = blockIdx.x & 63;
    const int ks = blockIdx.x >> 6;
    const int row0 = rg * TM;
    const int kbase = ks * KSEG;
    const int tid = threadIdx.x;
    const int tx = tid & 31;   // col:  c = tx + 32*j, j<5
    const int ty = tid >> 5;   // row:  r = ty + 8*i,  i<8

    float acc[8][5];
#pragma unroll
    for (int i = 0; i < 8; ++i)
#pragma unroll
        for (int j = 0; j < 5; ++j) acc[i][j] = 0.f;

    for (int kc = 0; kc < KSEG / KC; ++kc) {
        const int k0 = kbase + kc * KC;
        // stage x tile: 64 rows x 32 k  (512 float4 loads)
        for (int i = tid; i < TM * (KC / 4); i += 256) {
            int row = i >> 3, kq = i & 7;
            const float4 v = *(const float4*)&x[(size_t)(row0 + row) * DI + k0 + kq * 4];
            xs[row][kq * 4 + 0] = v.x;
            xs[row][kq * 4 + 1] = v.y;
            xs[row][kq * 4 + 2] = v.z;
            xs[row][kq * 4 + 3] = v.w;
        }
        // stage W tile (transposed): 160 cols x 32 k (1280 float4 loads)
        for (int i = tid; i < KXZ * (KC / 4); i += 256) {
            int c = i >> 3, kq = i & 7;
            const float4 v = *(const float4*)&Wx[(size_t)c * DI + k0 + kq * 4];
            wt[kq * 4 + 0][c] = v.x;
            wt[kq * 4 + 1][c] = v.y;
            wt[kq * 4 + 2][c] = v.z;
            wt[kq * 4 + 3][c] = v.w;
        }
        __syncthreads();
#pragma unroll 8
        for (int kk = 0; kk < KC; ++kk) {
            float wv[5], xv[8];
#pragma unroll
            for (int j = 0; j < 5; ++j) wv[j] = wt[kk][tx + 32 * j];
#pragma unroll
            for (int i = 0; i < 8; ++i) xv[i] = xs[ty + 8 * i][kk];
#pragma unroll
            for (int i = 0; i < 8; ++i)
#pragma unroll
                for (int j = 0; j < 5; ++j) acc[i][j] += xv[i] * wv[j];
        }
        __syncthreads();
    }
#pragma unroll
    for (int i = 0; i < 8; ++i)
#pragma unroll
        for (int j = 0; j < 5; ++j)
            atomicAdd(&xz[(size_t)(row0 + ty + 8 * i) * KXZ + tx + 32 * j], acc[i][j]);
}

// ---------------------------------------------------------------------------
// K2: dt[m][d] = softplus( sum_r xz[m][r] * W_dt[d][r] + b_dt[d] )
// Register-tiled: 64 rows x 64 cols per block, K=128 staged once in LDS
// in [k][row]/[k][col] transposed layout; each thread computes 4x4 via
// two ds_read_b128 per k. grid = 64 * 32 = 2048 blocks, 256 threads.
// ---------------------------------------------------------------------------
__global__ __launch_bounds__(256) void k_gemm_dt(const float* __restrict__ xz,
                                                 const float* __restrict__ Wdt,
                                                 const float* __restrict__ bdt,
                                                 float* __restrict__ dt) {
    __shared__ float rs[RR][64];    // [k][row]
    __shared__ float ws[RR][64];    // [k][col]
    const int m0 = (blockIdx.x & 63) * 64;
    const int d0 = (blockIdx.x >> 6) * 64;
    const int tid = threadIdx.x;
    const int lane = tid & 63;
    const int kq0 = (tid >> 6) * 8;     // 8 float4-k-chunks per thread

    // stage: lane = row/col index -> LDS write banks = lane mod 32 (2-way, free)
#pragma unroll
    for (int q = 0; q < 8; ++q) {
        const int kq = kq0 + q;
        const float4 v = *(const float4*)&xz[(size_t)(m0 + lane) * KXZ + kq * 4];
        rs[kq * 4 + 0][lane] = v.x;
        rs[kq * 4 + 1][lane] = v.y;
        rs[kq * 4 + 2][lane] = v.z;
        rs[kq * 4 + 3][lane] = v.w;
        const float4 w = *(const float4*)&Wdt[(size_t)(d0 + lane) * RR + kq * 4];
        ws[kq * 4 + 0][lane] = w.x;
        ws[kq * 4 + 1][lane] = w.y;
        ws[kq * 4 + 2][lane] = w.z;
        ws[kq * 4 + 3][lane] = w.w;
    }
    __syncthreads();

    const int tx = tid & 15;    // col group: cols tx*4 .. tx*4+3
    const int ty = tid >> 4;    // row group: rows ty*4 .. ty*4+3
    float acc[4][4];
#pragma unroll
    for (int i = 0; i < 4; ++i)
#pragma unroll
        for (int j = 0; j < 4; ++j) acc[i][j] = 0.f;

#pragma unroll 4
    for (int k = 0; k < RR; ++k) {
        const float4 xv = *(const float4*)&rs[k][ty * 4];
        const float4 wv = *(const float4*)&ws[k][tx * 4];
        const float xa[4] = {xv.x, xv.y, xv.z, xv.w};
        const float wa[4] = {wv.x, wv.y, wv.z, wv.w};
#pragma unroll
        for (int i = 0; i < 4; ++i)
#pragma unroll
            for (int j = 0; j < 4; ++j) acc[i][j] += xa[i] * wa[j];
    }

    const float4 bb4 = *(const float4*)&bdt[d0 + tx * 4];
    const float bb[4] = {bb4.x, bb4.y, bb4.z, bb4.w};
#pragma unroll
    for (int i = 0; i < 4; ++i) {
        float4 o;
        float* op = (float*)&o;
#pragma unroll
        for (int j = 0; j < 4; ++j) {
            float z = acc[i][j] + bb[j];
            op[j] = fmaxf(z, 0.f) + log1pf(__expf(-fabsf(z)));
        }
        *(float4*)&dt[(size_t)(m0 + ty * 4 + i) * DI + d0 + tx * 4] = o;
    }
}

// ---------------------------------------------------------------------------
// K3 (phase A): per (b, chunk, d): local zero-init scan over the chunk.
// Emits S = sum(dt) over chunk and the chunk-final local state LE[16].
// grid = B * NC * (DI/256) = 4*16*8 = 512 blocks, 256 threads
// ---------------------------------------------------------------------------
__global__ __launch_bounds__(256) void k_scan_a(const float* __restrict__ dt,
                                                const float* __restrict__ x,
                                                const float* __restrict__ xz,
                                                const float* __restrict__ A_log,
                                                float* __restrict__ Sws,
                                                float* __restrict__ LE) {
    const int bc = blockIdx.x;
    const int dg = bc & 7;
    const int c  = (bc >> 3) & 15;
    const int b  = bc >> 7;
    const int d  = dg * 256 + threadIdx.x;

    __shared__ float bs[LC * DS];
    for (int idx = threadIdx.x; idx < LC * DS; idx += 256) {
        int l = idx >> 4, n = idx & 15;
        bs[idx] = xz[((size_t)(b * L_ + c * LC + l)) * KXZ + RR + n];
    }
    float a[16];
#pragma unroll
    for (int n = 0; n < 16; ++n) a[n] = -__expf(A_log[(size_t)d * DS + n]);
    __syncthreads();

    float h[16];
#pragma unroll
    for (int n = 0; n < 16; ++n) h[n] = 0.f;
    float S = 0.f;
    const size_t base = ((size_t)b * L_ + c * LC) * DI + d;
    for (int l = 0; l < LC; ++l) {
        float dt_v = dt[base + (size_t)l * DI];
        float x_v  = x[base + (size_t)l * DI];
        S += dt_v;
        float dx = dt_v * x_v;
#pragma unroll
        for (int n = 0; n < 16; ++n)
            h[n] = __expf(dt_v * a[n]) * h[n] + dx * bs[l * 16 + n];
    }
    Sws[((size_t)b * NC + c) * DI + d] = S;
    const size_t leb = ((size_t)(b * NC + c) * DS) * DI + d;
#pragma unroll
    for (int n = 0; n < 16; ++n) LE[leb + (size_t)n * DI] = h[n];
}

// ---------------------------------------------------------------------------
// K4 (phase B): per (b,d): combine the 16 chunks sequentially; store the
// state ENTERING each chunk: H0[c] ; h <- exp(a*S_c)*h + LE_c
// grid = 32 blocks x 256
// ---------------------------------------------------------------------------
__global__ __launch_bounds__(256) void k_scan_b(const float* __restrict__ A_log,
                                                const float* __restrict__ Sws,
                                                const float* __restrict__ LE,
                                                float* __restrict__ H0) {
    const int idx = blockIdx.x * 256 + threadIdx.x;   // 0..8191
    const int d = idx & (DI - 1);
    const int b = idx >> 11;
    float a[16];
#pragma unroll
    for (int n = 0; n < 16; ++n) a[n] = -__expf(A_log[(size_t)d * DS + n]);
    float h[16];
#pragma unroll
    for (int n = 0; n < 16; ++n) h[n] = 0.f;
    for (int c = 0; c < NC; ++c) {
        const size_t hb = ((size_t)(b * NC + c) * DS) * DI + d;
#pragma unroll
        for (int n = 0; n < 16; ++n) H0[hb + (size_t)n * DI] = h[n];
        float S = Sws[((size_t)b * NC + c) * DI + d];
#pragma unroll
        for (int n = 0; n < 16; ++n)
            h[n] = __expf(a[n] * S) * h[n] + LE[hb + (size_t)n * DI];
    }
}

// ---------------------------------------------------------------------------
// K5 (phase C): full scan per chunk with correct initial state; fused
// y = c . h  and  out = y + x*D epilogue.
// grid = 512 blocks, 256 threads (same decode as K3)
// ---------------------------------------------------------------------------
__global__ __launch_bounds__(256) void k_scan_c(const float* __restrict__ dt,
                                                const float* __restrict__ x,
                                                const float* __restrict__ xz,
                                                const float* __restrict__ A_log,
                                                const float* __restrict__ H0,
                                                const float* __restrict__ Dp,
                                                float* __restrict__ out) {
    const int bc = blockIdx.x;
    const int dg = bc & 7;
    const int c  = (bc >> 3) & 15;
    const int b  = bc >> 7;
    const int d  = dg * 256 + threadIdx.x;

    __shared__ float bs[LC * DS];
    __shared__ float cs[LC * DS];
    for (int idx = threadIdx.x; idx < LC * DS; idx += 256) {
        int l = idx >> 4, n = idx & 15;
        const size_t rowb = ((size_t)(b * L_ + c * LC + l)) * KXZ;
        bs[idx] = xz[rowb + RR + n];
        cs[idx] = xz[rowb + RR + DS + n];
    }
    float a[16];
#pragma unroll
    for (int n = 0; n < 16; ++n) a[n] = -__expf(A_log[(size_t)d * DS + n]);
    float h[16];
    const size_t hb = ((size_t)(b * NC + c) * DS) * DI + d;
#pragma unroll
    for (int n = 0; n < 16; ++n) h[n] = H0[hb + (size_t)n * DI];
    const float Dv = Dp[d];
    __syncthreads();

    const size_t base = ((size_t)b * L_ + c * LC) * DI + d;
    for (int l = 0; l < LC; ++l) {
        float dt_v = dt[base + (size_t)l * DI];
        float x_v  = x[base + (size_t)l * DI];
        float dx = dt_v * x_v;
        float y = 0.f;
#pragma unroll
        for (int n = 0; n < 16; ++n) {
            h[n] = __expf(dt_v * a[n]) * h[n] + dx * bs[l * 16 + n];
            y += cs[l * 16 + n] * h[n];
        }
        out[base + (size_t)l * DI] = y + x_v * Dv;
    }
}

// ---------------------------------------------------------------------------
extern "C" void kernel_launch(void* const* d_in, const int* in_sizes, int n_in,
                              void* d_out, int out_size, void* d_ws, size_t ws_size,
                              hipStream_t stream) {
    const float* x     = (const float*)d_in[0];
    const float* Wx    = (const float*)d_in[1];
    const float* Wdt   = (const float*)d_in[2];
    const float* bdt   = (const float*)d_in[3];
    const float* A_log = (const float*)d_in[4];
    const float* Dp    = (const float*)d_in[5];
    float* out = (float*)d_out;

    float* ws = (float*)d_ws;
    float* xz  = ws;                                    // 4096*160      = 655360
    float* dt  = xz + (size_t)NROW * KXZ;               // 4096*2048     = 8388608
    float* Sws = dt + (size_t)NROW * DI;                // 4*16*2048     = 131072
    float* LE  = Sws + (size_t)B_ * NC * DI;            // 4*16*16*2048  = 2097152
    float* H0  = LE + (size_t)B_ * NC * DS * DI;        // 4*16*16*2048  = 2097152

    hipMemsetAsync(xz, 0, (size_t)NROW * KXZ * sizeof(float), stream);
    k_gemm_xz<<<(NROW / TM) * KS, 256, 0, stream>>>(x, Wx, xz);
    k_gemm_dt<<<(NROW / 64) * (DI / 64), 256, 0, stream>>>(xz, Wdt, bdt, dt);
    k_scan_a<<<B_ * NC * (DI / 256), 256, 0, stream>>>(dt, x, xz, A_log, Sws, LE);
    k_scan_b<<<B_ * DI / 256, 256, 0, stream>>>(A_log, Sws, LE, H0);
    k_scan_c<<<B_ * NC * (DI / 256), 256, 0, stream>>>(dt, x, xz, A_log, H0, Dp, out);
}

// Round 5
// 243.321 us; speedup vs baseline: 2.2610x; 1.2294x over previous
//
#include <hip/hip_runtime.h>
#include <hip/hip_bf16.h>
#include <math.h>

// Problem constants
#define B_ 4
#define L_ 1024
#define DI 2048
#define DS 16
#define RR 128          // DT_RANK
#define KXZ 160         // DT_RANK + 2*DS
#define NC 16           // chunks along L
#define LC 64           // chunk length
#define NROW (B_*L_)    // 4096

typedef __bf16 bf16x8 __attribute__((ext_vector_type(8)));
typedef float  f32x4  __attribute__((ext_vector_type(4)));

// ---------------------------------------------------------------------------
// K1: xz = x @ Wx^T  (M=4096, N=160, K=2048), bf16 MFMA, split-K x8.
// Block: 256 thr = 4 waves (2m x 2n), tile M=128 x N=160; wave = 64x80.
// Staging converts fp32->bf16. Partials accumulated via fp32 atomicAdd into
// xz (pre-zeroed by hipMemsetAsync each call) -- no aliasing, no state dep.
// grid = 32 row-groups * 8 ksplits = 256 blocks.
// ---------------------------------------------------------------------------
#define XKS 8
#define XKSEG (DI / XKS)   // 256

__global__ __launch_bounds__(256) void k_gemm_xz(const float* __restrict__ x,
                                                 const float* __restrict__ Wx,
                                                 float* __restrict__ xz) {
    __shared__ __bf16 As[128][32];
    __shared__ __bf16 Bs[160][32];
    const int rg = blockIdx.x & 31;
    const int ks = blockIdx.x >> 5;
    const int m0 = rg * 128;
    const int kb = ks * XKSEG;
    const int tid  = threadIdx.x;
    const int lane = tid & 63;
    const int w    = tid >> 6;
    const int mw = (w & 1) * 64;
    const int nw = (w >> 1) * 80;
    const int lm = lane & 15;
    const int quad = lane >> 4;

    f32x4 acc[4][5];
#pragma unroll
    for (int i = 0; i < 4; ++i)
#pragma unroll
        for (int j = 0; j < 5; ++j) acc[i][j] = (f32x4){0.f, 0.f, 0.f, 0.f};

    for (int st = 0; st < XKSEG / 32; ++st) {
        const int k0 = kb + st * 32;
        // stage A: 128 rows x 32 k  (1024 float4, coalesced 8 lanes/row)
#pragma unroll
        for (int i = 0; i < 4; ++i) {
            int idx = tid + 256 * i;
            int row = idx >> 3, kq = idx & 7;
            const float4 v = *(const float4*)&x[(size_t)(m0 + row) * DI + k0 + kq * 4];
            __bf16* dst = &As[row][kq * 4];
            dst[0] = (__bf16)v.x; dst[1] = (__bf16)v.y;
            dst[2] = (__bf16)v.z; dst[3] = (__bf16)v.w;
        }
        // stage B: 160 cols x 32 k  (1280 float4)
#pragma unroll
        for (int i = 0; i < 5; ++i) {
            int idx = tid + 256 * i;
            int col = idx >> 3, kq = idx & 7;
            const float4 v = *(const float4*)&Wx[(size_t)col * DI + k0 + kq * 4];
            __bf16* dst = &Bs[col][kq * 4];
            dst[0] = (__bf16)v.x; dst[1] = (__bf16)v.y;
            dst[2] = (__bf16)v.z; dst[3] = (__bf16)v.w;
        }
        __syncthreads();
        bf16x8 af[4], bf[5];
#pragma unroll
        for (int mi = 0; mi < 4; ++mi)
            af[mi] = *(const bf16x8*)&As[mw + mi * 16 + lm][quad * 8];
#pragma unroll
        for (int ni = 0; ni < 5; ++ni)
            bf[ni] = *(const bf16x8*)&Bs[nw + ni * 16 + lm][quad * 8];
#pragma unroll
        for (int mi = 0; mi < 4; ++mi)
#pragma unroll
            for (int ni = 0; ni < 5; ++ni)
                acc[mi][ni] = __builtin_amdgcn_mfma_f32_16x16x32_bf16(af[mi], bf[ni], acc[mi][ni], 0, 0, 0);
        __syncthreads();
    }
    // epilogue: accumulate fp32 partials into pre-zeroed xz
#pragma unroll
    for (int mi = 0; mi < 4; ++mi)
#pragma unroll
        for (int ni = 0; ni < 5; ++ni)
#pragma unroll
            for (int r = 0; r < 4; ++r) {
                int m = m0 + mw + mi * 16 + quad * 4 + r;
                int col = nw + ni * 16 + lm;
                atomicAdd(&xz[(size_t)m * KXZ + col], acc[mi][ni][r]);
            }
}

// ---------------------------------------------------------------------------
// K2: dt = softplus(xz[:, :128] @ Wdt^T + b), bf16 MFMA.
// M=4096, N=2048, K=128. Block 256 thr, tile 128x128, wave 64x64.
// grid = 32 * 16 = 512 blocks.
// ---------------------------------------------------------------------------
__global__ __launch_bounds__(256) void k_gemm_dt(const float* __restrict__ xz,
                                                 const float* __restrict__ Wdt,
                                                 const float* __restrict__ bdt,
                                                 float* __restrict__ dt) {
    __shared__ __bf16 As[128][32];
    __shared__ __bf16 Bs[128][32];
    const int m0 = (blockIdx.x & 31) * 128;
    const int d0 = (blockIdx.x >> 5) * 128;
    const int tid  = threadIdx.x;
    const int lane = tid & 63;
    const int w    = tid >> 6;
    const int mw = (w & 1) * 64;
    const int nw = (w >> 1) * 64;
    const int lm = lane & 15;
    const int quad = lane >> 4;

    f32x4 acc[4][4];
#pragma unroll
    for (int i = 0; i < 4; ++i)
#pragma unroll
        for (int j = 0; j < 4; ++j) acc[i][j] = (f32x4){0.f, 0.f, 0.f, 0.f};

    for (int st = 0; st < RR / 32; ++st) {
        const int k0 = st * 32;
#pragma unroll
        for (int i = 0; i < 4; ++i) {
            int idx = tid + 256 * i;
            int row = idx >> 3, kq = idx & 7;
            const float4 v = *(const float4*)&xz[(size_t)(m0 + row) * KXZ + k0 + kq * 4];
            __bf16* dst = &As[row][kq * 4];
            dst[0] = (__bf16)v.x; dst[1] = (__bf16)v.y;
            dst[2] = (__bf16)v.z; dst[3] = (__bf16)v.w;
        }
#pragma unroll
        for (int i = 0; i < 4; ++i) {
            int idx = tid + 256 * i;
            int row = idx >> 3, kq = idx & 7;
            const float4 v = *(const float4*)&Wdt[(size_t)(d0 + row) * RR + k0 + kq * 4];
            __bf16* dst = &Bs[row][kq * 4];
            dst[0] = (__bf16)v.x; dst[1] = (__bf16)v.y;
            dst[2] = (__bf16)v.z; dst[3] = (__bf16)v.w;
        }
        __syncthreads();
        bf16x8 af[4], bf[4];
#pragma unroll
        for (int mi = 0; mi < 4; ++mi)
            af[mi] = *(const bf16x8*)&As[mw + mi * 16 + lm][quad * 8];
#pragma unroll
        for (int ni = 0; ni < 4; ++ni)
            bf[ni] = *(const bf16x8*)&Bs[nw + ni * 16 + lm][quad * 8];
#pragma unroll
        for (int mi = 0; mi < 4; ++mi)
#pragma unroll
            for (int ni = 0; ni < 4; ++ni)
                acc[mi][ni] = __builtin_amdgcn_mfma_f32_16x16x32_bf16(af[mi], bf[ni], acc[mi][ni], 0, 0, 0);
        __syncthreads();
    }
    // epilogue: + bias, softplus, store fp32
#pragma unroll
    for (int ni = 0; ni < 4; ++ni) {
        const int col = d0 + nw + ni * 16 + lm;
        const float bb = bdt[col];
#pragma unroll
        for (int mi = 0; mi < 4; ++mi)
#pragma unroll
            for (int r = 0; r < 4; ++r) {
                int m = m0 + mw + mi * 16 + quad * 4 + r;
                float z = acc[mi][ni][r] + bb;
                dt[(size_t)m * DI + col] = fmaxf(z, 0.f) + log1pf(__expf(-fabsf(z)));
            }
    }
}

// ---------------------------------------------------------------------------
// K3 (phase A): per (b, chunk, d): local zero-init scan over the chunk.
// Emits S = sum(dt) over chunk and the chunk-final local state LE[16].
// grid = B * NC * (DI/256) = 4*16*8 = 512 blocks, 256 threads
// ---------------------------------------------------------------------------
__global__ __launch_bounds__(256) void k_scan_a(const float* __restrict__ dt,
                                                const float* __restrict__ x,
                                                const float* __restrict__ xz,
                                                const float* __restrict__ A_log,
                                                float* __restrict__ Sws,
                                                float* __restrict__ LE) {
    const int bc = blockIdx.x;
    const int dg = bc & 7;
    const int c  = (bc >> 3) & 15;
    const int b  = bc >> 7;
    const int d  = dg * 256 + threadIdx.x;

    __shared__ float bs[LC * DS];
    for (int idx = threadIdx.x; idx < LC * DS; idx += 256) {
        int l = idx >> 4, n = idx & 15;
        bs[idx] = xz[((size_t)(b * L_ + c * LC + l)) * KXZ + RR + n];
    }
    float a[16];
#pragma unroll
    for (int n = 0; n < 16; ++n) a[n] = -__expf(A_log[(size_t)d * DS + n]);
    __syncthreads();

    float h[16];
#pragma unroll
    for (int n = 0; n < 16; ++n) h[n] = 0.f;
    float S = 0.f;
    const size_t base = ((size_t)b * L_ + c * LC) * DI + d;
    for (int l = 0; l < LC; ++l) {
        float dt_v = dt[base + (size_t)l * DI];
        float x_v  = x[base + (size_t)l * DI];
        S += dt_v;
        float dx = dt_v * x_v;
#pragma unroll
        for (int n = 0; n < 16; ++n)
            h[n] = __expf(dt_v * a[n]) * h[n] + dx * bs[l * 16 + n];
    }
    Sws[((size_t)b * NC + c) * DI + d] = S;
    const size_t leb = ((size_t)(b * NC + c) * DS) * DI + d;
#pragma unroll
    for (int n = 0; n < 16; ++n) LE[leb + (size_t)n * DI] = h[n];
}

// ---------------------------------------------------------------------------
// K4 (phase B): per (b,d): combine the 16 chunks sequentially; store the
// state ENTERING each chunk: H0[c] ; h <- exp(a*S_c)*h + LE_c
// grid = 32 blocks x 256
// ---------------------------------------------------------------------------
__global__ __launch_bounds__(256) void k_scan_b(const float* __restrict__ A_log,
                                                const float* __restrict__ Sws,
                                                const float* __restrict__ LE,
                                                float* __restrict__ H0) {
    const int idx = blockIdx.x * 256 + threadIdx.x;   // 0..8191
    const int d = idx & (DI - 1);
    const int b = idx >> 11;
    float a[16];
#pragma unroll
    for (int n = 0; n < 16; ++n) a[n] = -__expf(A_log[(size_t)d * DS + n]);
    float h[16];
#pragma unroll
    for (int n = 0; n < 16; ++n) h[n] = 0.f;
    for (int c = 0; c < NC; ++c) {
        const size_t hb = ((size_t)(b * NC + c) * DS) * DI + d;
#pragma unroll
        for (int n = 0; n < 16; ++n) H0[hb + (size_t)n * DI] = h[n];
        float S = Sws[((size_t)b * NC + c) * DI + d];
#pragma unroll
        for (int n = 0; n < 16; ++n)
            h[n] = __expf(a[n] * S) * h[n] + LE[hb + (size_t)n * DI];
    }
}

// ---------------------------------------------------------------------------
// K5 (phase C): full scan per chunk with correct initial state; fused
// y = c . h  and  out = y + x*D epilogue.
// grid = 512 blocks, 256 threads (same decode as K3)
// ---------------------------------------------------------------------------
__global__ __launch_bounds__(256) void k_scan_c(const float* __restrict__ dt,
                                                const float* __restrict__ x,
                                                const float* __restrict__ xz,
                                                const float* __restrict__ A_log,
                                                const float* __restrict__ H0,
                                                const float* __restrict__ Dp,
                                                float* __restrict__ out) {
    const int bc = blockIdx.x;
    const int dg = bc & 7;
    const int c  = (bc >> 3) & 15;
    const int b  = bc >> 7;
    const int d  = dg * 256 + threadIdx.x;

    __shared__ float bs[LC * DS];
    __shared__ float cs[LC * DS];
    for (int idx = threadIdx.x; idx < LC * DS; idx += 256) {
        int l = idx >> 4, n = idx & 15;
        const size_t rowb = ((size_t)(b * L_ + c * LC + l)) * KXZ;
        bs[idx] = xz[rowb + RR + n];
        cs[idx] = xz[rowb + RR + DS + n];
    }
    float a[16];
#pragma unroll
    for (int n = 0; n < 16; ++n) a[n] = -__expf(A_log[(size_t)d * DS + n]);
    float h[16];
    const size_t hb = ((size_t)(b * NC + c) * DS) * DI + d;
#pragma unroll
    for (int n = 0; n < 16; ++n) h[n] = H0[hb + (size_t)n * DI];
    const float Dv = Dp[d];
    __syncthreads();

    const size_t base = ((size_t)b * L_ + c * LC) * DI + d;
    for (int l = 0; l < LC; ++l) {
        float dt_v = dt[base + (size_t)l * DI];
        float x_v  = x[base + (size_t)l * DI];
        float dx = dt_v * x_v;
        float y = 0.f;
#pragma unroll
        for (int n = 0; n < 16; ++n) {
            h[n] = __expf(dt_v * a[n]) * h[n] + dx * bs[l * 16 + n];
            y += cs[l * 16 + n] * h[n];
        }
        out[base + (size_t)l * DI] = y + x_v * Dv;
    }
}

// ---------------------------------------------------------------------------
extern "C" void kernel_launch(void* const* d_in, const int* in_sizes, int n_in,
                              void* d_out, int out_size, void* d_ws, size_t ws_size,
                              hipStream_t stream) {
    const float* x     = (const float*)d_in[0];
    const float* Wx    = (const float*)d_in[1];
    const float* Wdt   = (const float*)d_in[2];
    const float* bdt   = (const float*)d_in[3];
    const float* A_log = (const float*)d_in[4];
    const float* Dp    = (const float*)d_in[5];
    float* out = (float*)d_out;

    float* ws = (float*)d_ws;
    float* xz  = ws;                                    // 4096*160      = 655360
    float* dt  = xz + (size_t)NROW * KXZ;               // 4096*2048     = 8388608
    float* Sws = dt + (size_t)NROW * DI;                // 4*16*2048     = 131072
    float* LE  = Sws + (size_t)B_ * NC * DI;            // 4*16*16*2048  = 2097152
    float* H0  = LE + (size_t)B_ * NC * DS * DI;        // 4*16*16*2048  = 2097152

    hipMemsetAsync(xz, 0, (size_t)NROW * KXZ * sizeof(float), stream);
    k_gemm_xz<<<32 * XKS, 256, 0, stream>>>(x, Wx, xz);
    k_gemm_dt<<<32 * 16, 256, 0, stream>>>(xz, Wdt, bdt, dt);
    k_scan_a<<<B_ * NC * (DI / 256), 256, 0, stream>>>(dt, x, xz, A_log, Sws, LE);
    k_scan_b<<<B_ * DI / 256, 256, 0, stream>>>(A_log, Sws, LE, H0);
    k_scan_c<<<B_ * NC * (DI / 256), 256, 0, stream>>>(dt, x, xz, A_log, H0, Dp, out);
}

// Round 6
// 238.833 us; speedup vs baseline: 2.3035x; 1.0188x over previous
//
#include <hip/hip_runtime.h>
#include <hip/hip_bf16.h>
#include <math.h>

// Problem constants
#define B_ 4
#define L_ 1024
#define DI 2048
#define DS 16
#define RR 128          // DT_RANK
#define KXZ 160         // DT_RANK + 2*DS
#define NC 16           // chunks along L
#define LC 64           // chunk length
#define NROW (B_*L_)    // 4096

typedef __bf16 bf16x8 __attribute__((ext_vector_type(8)));
typedef __bf16 bf16x4 __attribute__((ext_vector_type(4)));
typedef float  f32x4  __attribute__((ext_vector_type(4)));

// ---------------------------------------------------------------------------
// K1: xz = x @ Wx^T  (M=4096, N=160, K=2048), bf16 MFMA, split-K x8.
// Partials accumulated via fp32 atomicAdd into pre-zeroed xz.
// grid = 32 row-groups * 8 ksplits = 256 blocks. (proven R5 version)
// ---------------------------------------------------------------------------
#define XKS 8
#define XKSEG (DI / XKS)   // 256

__global__ __launch_bounds__(256) void k_gemm_xz(const float* __restrict__ x,
                                                 const float* __restrict__ Wx,
                                                 float* __restrict__ xz) {
    __shared__ __bf16 As[128][32];
    __shared__ __bf16 Bs[160][32];
    const int rg = blockIdx.x & 31;
    const int ks = blockIdx.x >> 5;
    const int m0 = rg * 128;
    const int kb = ks * XKSEG;
    const int tid  = threadIdx.x;
    const int lane = tid & 63;
    const int w    = tid >> 6;
    const int mw = (w & 1) * 64;
    const int nw = (w >> 1) * 80;
    const int lm = lane & 15;
    const int quad = lane >> 4;

    f32x4 acc[4][5];
#pragma unroll
    for (int i = 0; i < 4; ++i)
#pragma unroll
        for (int j = 0; j < 5; ++j) acc[i][j] = (f32x4){0.f, 0.f, 0.f, 0.f};

    for (int st = 0; st < XKSEG / 32; ++st) {
        const int k0 = kb + st * 32;
#pragma unroll
        for (int i = 0; i < 4; ++i) {
            int idx = tid + 256 * i;
            int row = idx >> 3, kq = idx & 7;
            const float4 v = *(const float4*)&x[(size_t)(m0 + row) * DI + k0 + kq * 4];
            bf16x4 p = {(__bf16)v.x, (__bf16)v.y, (__bf16)v.z, (__bf16)v.w};
            *(bf16x4*)&As[row][kq * 4] = p;
        }
#pragma unroll
        for (int i = 0; i < 5; ++i) {
            int idx = tid + 256 * i;
            int col = idx >> 3, kq = idx & 7;
            const float4 v = *(const float4*)&Wx[(size_t)col * DI + k0 + kq * 4];
            bf16x4 p = {(__bf16)v.x, (__bf16)v.y, (__bf16)v.z, (__bf16)v.w};
            *(bf16x4*)&Bs[col][kq * 4] = p;
        }
        __syncthreads();
        bf16x8 af[4], bf[5];
#pragma unroll
        for (int mi = 0; mi < 4; ++mi)
            af[mi] = *(const bf16x8*)&As[mw + mi * 16 + lm][quad * 8];
#pragma unroll
        for (int ni = 0; ni < 5; ++ni)
            bf[ni] = *(const bf16x8*)&Bs[nw + ni * 16 + lm][quad * 8];
#pragma unroll
        for (int mi = 0; mi < 4; ++mi)
#pragma unroll
            for (int ni = 0; ni < 5; ++ni)
                acc[mi][ni] = __builtin_amdgcn_mfma_f32_16x16x32_bf16(af[mi], bf[ni], acc[mi][ni], 0, 0, 0);
        __syncthreads();
    }
#pragma unroll
    for (int mi = 0; mi < 4; ++mi)
#pragma unroll
        for (int ni = 0; ni < 5; ++ni)
#pragma unroll
            for (int r = 0; r < 4; ++r) {
                int m = m0 + mw + mi * 16 + quad * 4 + r;
                int col = nw + ni * 16 + lm;
                atomicAdd(&xz[(size_t)m * KXZ + col], acc[mi][ni][r]);
            }
}

// ---------------------------------------------------------------------------
// K2: dt = softplus(xz[:, :128] @ Wdt^T + b), bf16 MFMA.
// M=4096, N=2048, K=128. Tile 64x128, K staged once (no inner barriers).
// 4 waves = 2m x 2n (wave tile 32x64). Epilogue transposes C through LDS
// and stores fully-coalesced float4 (2 x 512B contiguous per wave-store).
// grid = 64 m-tiles * 16 n-tiles = 1024 blocks.
// ---------------------------------------------------------------------------
__global__ __launch_bounds__(256) void k_gemm_dt(const float* __restrict__ xz,
                                                 const float* __restrict__ Wdt,
                                                 const float* __restrict__ bdt,
                                                 float* __restrict__ dt) {
    __shared__ __align__(16) unsigned char smem[49152];
    __bf16 (*As)[128] = (__bf16(*)[128])smem;            // 64 x 128 bf16 = 16 KB
    __bf16 (*Bs)[128] = (__bf16(*)[128])(smem + 16384);  // 128 x 128 bf16 = 32 KB
    float  (*ep)[132] = (float(*)[132])smem;             // 64 x 132 fp32 = 33.8 KB (reuse)

    const int m0 = (blockIdx.x & 63) * 64;
    const int d0 = (blockIdx.x >> 6) * 128;
    const int tid  = threadIdx.x;
    const int lane = tid & 63;
    const int w    = tid >> 6;
    const int mw = (w & 1) * 32;
    const int nw = (w >> 1) * 64;
    const int lm = lane & 15;
    const int quad = lane >> 4;

    // stage A: 64 rows x 128 k (8 float4/thread)
#pragma unroll
    for (int i = 0; i < 8; ++i) {
        int idx = tid + 256 * i;
        int row = idx >> 5, c4 = idx & 31;
        const float4 v = *(const float4*)&xz[(size_t)(m0 + row) * KXZ + c4 * 4];
        bf16x4 p = {(__bf16)v.x, (__bf16)v.y, (__bf16)v.z, (__bf16)v.w};
        *(bf16x4*)&As[row][c4 * 4] = p;
    }
    // stage B: 128 rows x 128 k (16 float4/thread)
#pragma unroll
    for (int i = 0; i < 16; ++i) {
        int idx = tid + 256 * i;
        int row = idx >> 5, c4 = idx & 31;
        const float4 v = *(const float4*)&Wdt[(size_t)(d0 + row) * RR + c4 * 4];
        bf16x4 p = {(__bf16)v.x, (__bf16)v.y, (__bf16)v.z, (__bf16)v.w};
        *(bf16x4*)&Bs[row][c4 * 4] = p;
    }
    __syncthreads();

    f32x4 acc[2][4];
#pragma unroll
    for (int i = 0; i < 2; ++i)
#pragma unroll
        for (int j = 0; j < 4; ++j) acc[i][j] = (f32x4){0.f, 0.f, 0.f, 0.f};

#pragma unroll
    for (int ks = 0; ks < 4; ++ks) {
        bf16x8 af[2], bf[4];
#pragma unroll
        for (int mi = 0; mi < 2; ++mi)
            af[mi] = *(const bf16x8*)&As[mw + mi * 16 + lm][ks * 32 + quad * 8];
#pragma unroll
        for (int ni = 0; ni < 4; ++ni)
            bf[ni] = *(const bf16x8*)&Bs[nw + ni * 16 + lm][ks * 32 + quad * 8];
#pragma unroll
        for (int mi = 0; mi < 2; ++mi)
#pragma unroll
            for (int ni = 0; ni < 4; ++ni)
                acc[mi][ni] = __builtin_amdgcn_mfma_f32_16x16x32_bf16(af[mi], bf[ni], acc[mi][ni], 0, 0, 0);
    }
    __syncthreads();   // done with As/Bs; reuse as ep

    // C-frag -> LDS (row = mw+mi*16+quad*4+r, col = nw+ni*16+lm)
#pragma unroll
    for (int mi = 0; mi < 2; ++mi)
#pragma unroll
        for (int ni = 0; ni < 4; ++ni)
#pragma unroll
            for (int r = 0; r < 4; ++r)
                ep[mw + mi * 16 + quad * 4 + r][nw + ni * 16 + lm] = acc[mi][ni][r];
    __syncthreads();

    // coalesced store: 8 float4/thread, softplus fused
#pragma unroll
    for (int i = 0; i < 8; ++i) {
        int idx = tid + 256 * i;
        int row = idx >> 5, c4 = idx & 31;
        const f32x4 v = *(const f32x4*)&ep[row][c4 * 4];
        const float4 bb = *(const float4*)&bdt[d0 + c4 * 4];
        f32x4 o;
        float z0 = v[0] + bb.x; o[0] = fmaxf(z0, 0.f) + log1pf(__expf(-fabsf(z0)));
        float z1 = v[1] + bb.y; o[1] = fmaxf(z1, 0.f) + log1pf(__expf(-fabsf(z1)));
        float z2 = v[2] + bb.z; o[2] = fmaxf(z2, 0.f) + log1pf(__expf(-fabsf(z2)));
        float z3 = v[3] + bb.w; o[3] = fmaxf(z3, 0.f) + log1pf(__expf(-fabsf(z3)));
        *(f32x4*)&dt[(size_t)(m0 + row) * DI + d0 + c4 * 4] = o;
    }
}

// ---------------------------------------------------------------------------
// K3 (phase A): per (b, chunk, d): local zero-init scan over the chunk.
// Emits S = sum(dt) over chunk and the chunk-final local state LE[16].
// grid = B * NC * (DI/256) = 512 blocks, 256 threads
// ---------------------------------------------------------------------------
__global__ __launch_bounds__(256) void k_scan_a(const float* __restrict__ dt,
                                                const float* __restrict__ x,
                                                const float* __restrict__ xz,
                                                const float* __restrict__ A_log,
                                                float* __restrict__ Sws,
                                                float* __restrict__ LE) {
    const int bc = blockIdx.x;
    const int dg = bc & 7;
    const int c  = (bc >> 3) & 15;
    const int b  = bc >> 7;
    const int d  = dg * 256 + threadIdx.x;

    __shared__ float bs[LC * DS];
    for (int idx = threadIdx.x; idx < LC * DS; idx += 256) {
        int l = idx >> 4, n = idx & 15;
        bs[idx] = xz[((size_t)(b * L_ + c * LC + l)) * KXZ + RR + n];
    }
    float a[16];
#pragma unroll
    for (int n = 0; n < 16; ++n) a[n] = -__expf(A_log[(size_t)d * DS + n]);
    __syncthreads();

    float h[16];
#pragma unroll
    for (int n = 0; n < 16; ++n) h[n] = 0.f;
    float S = 0.f;
    const size_t base = ((size_t)b * L_ + c * LC) * DI + d;
    for (int l = 0; l < LC; ++l) {
        float dt_v = dt[base + (size_t)l * DI];
        float x_v  = x[base + (size_t)l * DI];
        S += dt_v;
        float dx = dt_v * x_v;
#pragma unroll
        for (int n = 0; n < 16; ++n)
            h[n] = __expf(dt_v * a[n]) * h[n] + dx * bs[l * 16 + n];
    }
    Sws[((size_t)b * NC + c) * DI + d] = S;
    const size_t leb = ((size_t)(b * NC + c) * DS) * DI + d;
#pragma unroll
    for (int n = 0; n < 16; ++n) LE[leb + (size_t)n * DI] = h[n];
}

// ---------------------------------------------------------------------------
// K4 (phase B): per (b,d): combine the 16 chunks sequentially; store the
// state ENTERING each chunk: H0[c] ; h <- exp(a*S_c)*h + LE_c
// grid = 32 blocks x 256
// ---------------------------------------------------------------------------
__global__ __launch_bounds__(256) void k_scan_b(const float* __restrict__ A_log,
                                                const float* __restrict__ Sws,
                                                const float* __restrict__ LE,
                                                float* __restrict__ H0) {
    const int idx = blockIdx.x * 256 + threadIdx.x;   // 0..8191
    const int d = idx & (DI - 1);
    const int b = idx >> 11;
    float a[16];
#pragma unroll
    for (int n = 0; n < 16; ++n) a[n] = -__expf(A_log[(size_t)d * DS + n]);
    float h[16];
#pragma unroll
    for (int n = 0; n < 16; ++n) h[n] = 0.f;
    for (int c = 0; c < NC; ++c) {
        const size_t hb = ((size_t)(b * NC + c) * DS) * DI + d;
#pragma unroll
        for (int n = 0; n < 16; ++n) H0[hb + (size_t)n * DI] = h[n];
        float S = Sws[((size_t)b * NC + c) * DI + d];
#pragma unroll
        for (int n = 0; n < 16; ++n)
            h[n] = __expf(a[n] * S) * h[n] + LE[hb + (size_t)n * DI];
    }
}

// ---------------------------------------------------------------------------
// K5 (phase C): full scan per chunk with correct initial state; fused
// y = c . h  and  out = y + x*D epilogue.
// grid = 512 blocks, 256 threads (same decode as K3)
// ---------------------------------------------------------------------------
__global__ __launch_bounds__(256) void k_scan_c(const float* __restrict__ dt,
                                                const float* __restrict__ x,
                                                const float* __restrict__ xz,
                                                const float* __restrict__ A_log,
                                                const float* __restrict__ H0,
                                                const float* __restrict__ Dp,
                                                float* __restrict__ out) {
    const int bc = blockIdx.x;
    const int dg = bc & 7;
    const int c  = (bc >> 3) & 15;
    const int b  = bc >> 7;
    const int d  = dg * 256 + threadIdx.x;

    __shared__ float bs[LC * DS];
    __shared__ float cs[LC * DS];
    for (int idx = threadIdx.x; idx < LC * DS; idx += 256) {
        int l = idx >> 4, n = idx & 15;
        const size_t rowb = ((size_t)(b * L_ + c * LC + l)) * KXZ;
        bs[idx] = xz[rowb + RR + n];
        cs[idx] = xz[rowb + RR + DS + n];
    }
    float a[16];
#pragma unroll
    for (int n = 0; n < 16; ++n) a[n] = -__expf(A_log[(size_t)d * DS + n]);
    float h[16];
    const size_t hb = ((size_t)(b * NC + c) * DS) * DI + d;
#pragma unroll
    for (int n = 0; n < 16; ++n) h[n] = H0[hb + (size_t)n * DI];
    const float Dv = Dp[d];
    __syncthreads();

    const size_t base = ((size_t)b * L_ + c * LC) * DI + d;
    for (int l = 0; l < LC; ++l) {
        float dt_v = dt[base + (size_t)l * DI];
        float x_v  = x[base + (size_t)l * DI];
        float dx = dt_v * x_v;
        float y = 0.f;
#pragma unroll
        for (int n = 0; n < 16; ++n) {
            h[n] = __expf(dt_v * a[n]) * h[n] + dx * bs[l * 16 + n];
            y += cs[l * 16 + n] * h[n];
        }
        out[base + (size_t)l * DI] = y + x_v * Dv;
    }
}

// ---------------------------------------------------------------------------
extern "C" void kernel_launch(void* const* d_in, const int* in_sizes, int n_in,
                              void* d_out, int out_size, void* d_ws, size_t ws_size,
                              hipStream_t stream) {
    const float* x     = (const float*)d_in[0];
    const float* Wx    = (const float*)d_in[1];
    const float* Wdt   = (const float*)d_in[2];
    const float* bdt   = (const float*)d_in[3];
    const float* A_log = (const float*)d_in[4];
    const float* Dp    = (const float*)d_in[5];
    float* out = (float*)d_out;

    float* ws = (float*)d_ws;
    float* xz  = ws;                                    // 4096*160      = 655360
    float* dt  = xz + (size_t)NROW * KXZ;               // 4096*2048     = 8388608
    float* Sws = dt + (size_t)NROW * DI;                // 4*16*2048     = 131072
    float* LE  = Sws + (size_t)B_ * NC * DI;            // 4*16*16*2048  = 2097152
    float* H0  = LE + (size_t)B_ * NC * DS * DI;        // 4*16*16*2048  = 2097152

    hipMemsetAsync(xz, 0, (size_t)NROW * KXZ * sizeof(float), stream);
    k_gemm_xz<<<32 * XKS, 256, 0, stream>>>(x, Wx, xz);
    k_gemm_dt<<<64 * 16, 256, 0, stream>>>(xz, Wdt, bdt, dt);
    k_scan_a<<<B_ * NC * (DI / 256), 256, 0, stream>>>(dt, x, xz, A_log, Sws, LE);
    k_scan_b<<<B_ * DI / 256, 256, 0, stream>>>(A_log, Sws, LE, H0);
    k_scan_c<<<B_ * NC * (DI / 256), 256, 0, stream>>>(dt, x, xz, A_log, H0, Dp, out);
}

// Round 7
// 235.334 us; speedup vs baseline: 2.3378x; 1.0149x over previous
//
#include <hip/hip_runtime.h>
#include <hip/hip_bf16.h>
#include <math.h>

// Problem constants
#define B_ 4
#define L_ 1024
#define DI 2048
#define DS 16
#define RR 128          // DT_RANK
#define KXZ 160         // DT_RANK + 2*DS
#define NROW (B_*L_)    // 4096

typedef __bf16 bf16x8 __attribute__((ext_vector_type(8)));
typedef __bf16 bf16x4 __attribute__((ext_vector_type(4)));
typedef float  f32x4  __attribute__((ext_vector_type(4)));

// ---------------------------------------------------------------------------
// K1: xz = x @ Wx^T  (M=4096, N=160, K=2048), bf16 MFMA, split-K x8.
// Partials accumulated via fp32 atomicAdd into pre-zeroed xz.
// grid = 32 row-groups * 8 ksplits = 256 blocks. (proven R5 version)
// ---------------------------------------------------------------------------
#define XKS 8
#define XKSEG (DI / XKS)   // 256

__global__ __launch_bounds__(256) void k_gemm_xz(const float* __restrict__ x,
                                                 const float* __restrict__ Wx,
                                                 float* __restrict__ xz) {
    __shared__ __bf16 As[128][32];
    __shared__ __bf16 Bs[160][32];
    const int rg = blockIdx.x & 31;
    const int ks = blockIdx.x >> 5;
    const int m0 = rg * 128;
    const int kb = ks * XKSEG;
    const int tid  = threadIdx.x;
    const int lane = tid & 63;
    const int w    = tid >> 6;
    const int mw = (w & 1) * 64;
    const int nw = (w >> 1) * 80;
    const int lm = lane & 15;
    const int quad = lane >> 4;

    f32x4 acc[4][5];
#pragma unroll
    for (int i = 0; i < 4; ++i)
#pragma unroll
        for (int j = 0; j < 5; ++j) acc[i][j] = (f32x4){0.f, 0.f, 0.f, 0.f};

    for (int st = 0; st < XKSEG / 32; ++st) {
        const int k0 = kb + st * 32;
#pragma unroll
        for (int i = 0; i < 4; ++i) {
            int idx = tid + 256 * i;
            int row = idx >> 3, kq = idx & 7;
            const float4 v = *(const float4*)&x[(size_t)(m0 + row) * DI + k0 + kq * 4];
            bf16x4 p = {(__bf16)v.x, (__bf16)v.y, (__bf16)v.z, (__bf16)v.w};
            *(bf16x4*)&As[row][kq * 4] = p;
        }
#pragma unroll
        for (int i = 0; i < 5; ++i) {
            int idx = tid + 256 * i;
            int col = idx >> 3, kq = idx & 7;
            const float4 v = *(const float4*)&Wx[(size_t)col * DI + k0 + kq * 4];
            bf16x4 p = {(__bf16)v.x, (__bf16)v.y, (__bf16)v.z, (__bf16)v.w};
            *(bf16x4*)&Bs[col][kq * 4] = p;
        }
        __syncthreads();
        bf16x8 af[4], bf[5];
#pragma unroll
        for (int mi = 0; mi < 4; ++mi)
            af[mi] = *(const bf16x8*)&As[mw + mi * 16 + lm][quad * 8];
#pragma unroll
        for (int ni = 0; ni < 5; ++ni)
            bf[ni] = *(const bf16x8*)&Bs[nw + ni * 16 + lm][quad * 8];
#pragma unroll
        for (int mi = 0; mi < 4; ++mi)
#pragma unroll
            for (int ni = 0; ni < 5; ++ni)
                acc[mi][ni] = __builtin_amdgcn_mfma_f32_16x16x32_bf16(af[mi], bf[ni], acc[mi][ni], 0, 0, 0);
        __syncthreads();
    }
#pragma unroll
    for (int mi = 0; mi < 4; ++mi)
#pragma unroll
        for (int ni = 0; ni < 5; ++ni)
#pragma unroll
            for (int r = 0; r < 4; ++r) {
                int m = m0 + mw + mi * 16 + quad * 4 + r;
                int col = nw + ni * 16 + lm;
                atomicAdd(&xz[(size_t)m * KXZ + col], acc[mi][ni][r]);
            }
}

// ---------------------------------------------------------------------------
// K2: dt = softplus(xz[:, :128] @ Wdt^T + b), bf16 MFMA, 64x128 tile,
// LDS-transpose epilogue with coalesced float4 stores. (proven R6 version)
// grid = 64 * 16 = 1024 blocks.
// ---------------------------------------------------------------------------
__global__ __launch_bounds__(256) void k_gemm_dt(const float* __restrict__ xz,
                                                 const float* __restrict__ Wdt,
                                                 const float* __restrict__ bdt,
                                                 float* __restrict__ dt) {
    __shared__ __align__(16) unsigned char smem[49152];
    __bf16 (*As)[128] = (__bf16(*)[128])smem;            // 64 x 128 bf16
    __bf16 (*Bs)[128] = (__bf16(*)[128])(smem + 16384);  // 128 x 128 bf16
    float  (*ep)[132] = (float(*)[132])smem;             // 64 x 132 fp32 (reuse)

    const int m0 = (blockIdx.x & 63) * 64;
    const int d0 = (blockIdx.x >> 6) * 128;
    const int tid  = threadIdx.x;
    const int lane = tid & 63;
    const int w    = tid >> 6;
    const int mw = (w & 1) * 32;
    const int nw = (w >> 1) * 64;
    const int lm = lane & 15;
    const int quad = lane >> 4;

#pragma unroll
    for (int i = 0; i < 8; ++i) {
        int idx = tid + 256 * i;
        int row = idx >> 5, c4 = idx & 31;
        const float4 v = *(const float4*)&xz[(size_t)(m0 + row) * KXZ + c4 * 4];
        bf16x4 p = {(__bf16)v.x, (__bf16)v.y, (__bf16)v.z, (__bf16)v.w};
        *(bf16x4*)&As[row][c4 * 4] = p;
    }
#pragma unroll
    for (int i = 0; i < 16; ++i) {
        int idx = tid + 256 * i;
        int row = idx >> 5, c4 = idx & 31;
        const float4 v = *(const float4*)&Wdt[(size_t)(d0 + row) * RR + c4 * 4];
        bf16x4 p = {(__bf16)v.x, (__bf16)v.y, (__bf16)v.z, (__bf16)v.w};
        *(bf16x4*)&Bs[row][c4 * 4] = p;
    }
    __syncthreads();

    f32x4 acc[2][4];
#pragma unroll
    for (int i = 0; i < 2; ++i)
#pragma unroll
        for (int j = 0; j < 4; ++j) acc[i][j] = (f32x4){0.f, 0.f, 0.f, 0.f};

#pragma unroll
    for (int ks = 0; ks < 4; ++ks) {
        bf16x8 af[2], bf[4];
#pragma unroll
        for (int mi = 0; mi < 2; ++mi)
            af[mi] = *(const bf16x8*)&As[mw + mi * 16 + lm][ks * 32 + quad * 8];
#pragma unroll
        for (int ni = 0; ni < 4; ++ni)
            bf[ni] = *(const bf16x8*)&Bs[nw + ni * 16 + lm][ks * 32 + quad * 8];
#pragma unroll
        for (int mi = 0; mi < 2; ++mi)
#pragma unroll
            for (int ni = 0; ni < 4; ++ni)
                acc[mi][ni] = __builtin_amdgcn_mfma_f32_16x16x32_bf16(af[mi], bf[ni], acc[mi][ni], 0, 0, 0);
    }
    __syncthreads();

#pragma unroll
    for (int mi = 0; mi < 2; ++mi)
#pragma unroll
        for (int ni = 0; ni < 4; ++ni)
#pragma unroll
            for (int r = 0; r < 4; ++r)
                ep[mw + mi * 16 + quad * 4 + r][nw + ni * 16 + lm] = acc[mi][ni][r];
    __syncthreads();

#pragma unroll
    for (int i = 0; i < 8; ++i) {
        int idx = tid + 256 * i;
        int row = idx >> 5, c4 = idx & 31;
        const f32x4 v = *(const f32x4*)&ep[row][c4 * 4];
        const float4 bb = *(const float4*)&bdt[d0 + c4 * 4];
        f32x4 o;
        float z0 = v[0] + bb.x; o[0] = fmaxf(z0, 0.f) + log1pf(__expf(-fabsf(z0)));
        float z1 = v[1] + bb.y; o[1] = fmaxf(z1, 0.f) + log1pf(__expf(-fabsf(z1)));
        float z2 = v[2] + bb.z; o[2] = fmaxf(z2, 0.f) + log1pf(__expf(-fabsf(z2)));
        float z3 = v[3] + bb.w; o[3] = fmaxf(z3, 0.f) + log1pf(__expf(-fabsf(z3)));
        *(f32x4*)&dt[(size_t)(m0 + row) * DI + d0 + c4 * 4] = o;
    }
}

// ---------------------------------------------------------------------------
// K3 (phase A): per (b, chunk, d): local zero-init scan over the chunk.
// nc runtime (16 or 32) via ncshift; lc = 1024 >> ncshift.
// grid = B * nc * 8 blocks, 256 threads
// ---------------------------------------------------------------------------
__global__ __launch_bounds__(256) void k_scan_a(const float* __restrict__ dt,
                                                const float* __restrict__ x,
                                                const float* __restrict__ xz,
                                                const float* __restrict__ A_log,
                                                float* __restrict__ Sws,
                                                float* __restrict__ LE,
                                                const int ncshift) {
    const int nc = 1 << ncshift;
    const int lc = L_ >> ncshift;
    const int dg = blockIdx.x & 7;
    const int rest = blockIdx.x >> 3;
    const int c = rest & (nc - 1);
    const int b = rest >> ncshift;
    const int d = dg * 256 + threadIdx.x;

    __shared__ float bs[64 * DS];
    for (int idx = threadIdx.x; idx < lc * DS; idx += 256) {
        int l = idx >> 4, n = idx & 15;
        bs[idx] = xz[((size_t)(b * L_ + c * lc + l)) * KXZ + RR + n];
    }
    float a[16];
#pragma unroll
    for (int n = 0; n < 16; ++n) a[n] = -__expf(A_log[(size_t)d * DS + n]);
    __syncthreads();

    float h[16];
#pragma unroll
    for (int n = 0; n < 16; ++n) h[n] = 0.f;
    float S = 0.f;
    const size_t base = ((size_t)b * L_ + c * lc) * DI + d;
    float dt_v = dt[base];
    float x_v  = x[base];
    for (int l = 0; l < lc; ++l) {
        float dt_nx = 0.f, x_nx = 0.f;
        if (l + 1 < lc) {
            dt_nx = dt[base + (size_t)(l + 1) * DI];
            x_nx  = x[base + (size_t)(l + 1) * DI];
        }
        S += dt_v;
        float dx = dt_v * x_v;
#pragma unroll
        for (int n = 0; n < 16; ++n)
            h[n] = __expf(dt_v * a[n]) * h[n] + dx * bs[l * 16 + n];
        dt_v = dt_nx; x_v = x_nx;
    }
    Sws[((size_t)b * nc + c) * DI + d] = S;
    const size_t leb = ((size_t)(b * nc + c) * DS) * DI + d;
#pragma unroll
    for (int n = 0; n < 16; ++n) LE[leb + (size_t)n * DI] = h[n];
}

// ---------------------------------------------------------------------------
// K4 (phase B): per (b,d): combine chunks sequentially; store the state
// ENTERING each chunk. grid = 32 blocks x 256
// ---------------------------------------------------------------------------
__global__ __launch_bounds__(256) void k_scan_b(const float* __restrict__ A_log,
                                                const float* __restrict__ Sws,
                                                const float* __restrict__ LE,
                                                float* __restrict__ H0,
                                                const int ncshift) {
    const int nc = 1 << ncshift;
    const int idx = blockIdx.x * 256 + threadIdx.x;   // 0..8191
    const int d = idx & (DI - 1);
    const int b = idx >> 11;
    float a[16];
#pragma unroll
    for (int n = 0; n < 16; ++n) a[n] = -__expf(A_log[(size_t)d * DS + n]);
    float h[16];
#pragma unroll
    for (int n = 0; n < 16; ++n) h[n] = 0.f;
    for (int c = 0; c < nc; ++c) {
        const size_t hb = ((size_t)(b * nc + c) * DS) * DI + d;
#pragma unroll
        for (int n = 0; n < 16; ++n) H0[hb + (size_t)n * DI] = h[n];
        float S = Sws[((size_t)b * nc + c) * DI + d];
#pragma unroll
        for (int n = 0; n < 16; ++n)
            h[n] = __expf(a[n] * S) * h[n] + LE[hb + (size_t)n * DI];
    }
}

// ---------------------------------------------------------------------------
// K5 (phase C): full scan per chunk with correct initial state; fused
// y = c . h  and  out = y + x*D epilogue. grid = B * nc * 8 blocks.
// ---------------------------------------------------------------------------
__global__ __launch_bounds__(256) void k_scan_c(const float* __restrict__ dt,
                                                const float* __restrict__ x,
                                                const float* __restrict__ xz,
                                                const float* __restrict__ A_log,
                                                const float* __restrict__ H0,
                                                const float* __restrict__ Dp,
                                                float* __restrict__ out,
                                                const int ncshift) {
    const int nc = 1 << ncshift;
    const int lc = L_ >> ncshift;
    const int dg = blockIdx.x & 7;
    const int rest = blockIdx.x >> 3;
    const int c = rest & (nc - 1);
    const int b = rest >> ncshift;
    const int d = dg * 256 + threadIdx.x;

    __shared__ float bs[64 * DS];
    __shared__ float cs[64 * DS];
    for (int idx = threadIdx.x; idx < lc * DS; idx += 256) {
        int l = idx >> 4, n = idx & 15;
        const size_t rowb = ((size_t)(b * L_ + c * lc + l)) * KXZ;
        bs[idx] = xz[rowb + RR + n];
        cs[idx] = xz[rowb + RR + DS + n];
    }
    float a[16];
#pragma unroll
    for (int n = 0; n < 16; ++n) a[n] = -__expf(A_log[(size_t)d * DS + n]);
    float h[16];
    const size_t hb = ((size_t)(b * nc + c) * DS) * DI + d;
#pragma unroll
    for (int n = 0; n < 16; ++n) h[n] = H0[hb + (size_t)n * DI];
    const float Dv = Dp[d];
    __syncthreads();

    const size_t base = ((size_t)b * L_ + c * lc) * DI + d;
    float dt_v = dt[base];
    float x_v  = x[base];
    for (int l = 0; l < lc; ++l) {
        float dt_nx = 0.f, x_nx = 0.f;
        if (l + 1 < lc) {
            dt_nx = dt[base + (size_t)(l + 1) * DI];
            x_nx  = x[base + (size_t)(l + 1) * DI];
        }
        float dx = dt_v * x_v;
        float y0 = 0.f, y1 = 0.f, y2 = 0.f, y3 = 0.f;
#pragma unroll
        for (int n = 0; n < 16; n += 4) {
            h[n]     = __expf(dt_v * a[n])     * h[n]     + dx * bs[l * 16 + n];
            h[n + 1] = __expf(dt_v * a[n + 1]) * h[n + 1] + dx * bs[l * 16 + n + 1];
            h[n + 2] = __expf(dt_v * a[n + 2]) * h[n + 2] + dx * bs[l * 16 + n + 2];
            h[n + 3] = __expf(dt_v * a[n + 3]) * h[n + 3] + dx * bs[l * 16 + n + 3];
            y0 += cs[l * 16 + n] * h[n];
            y1 += cs[l * 16 + n + 1] * h[n + 1];
            y2 += cs[l * 16 + n + 2] * h[n + 2];
            y3 += cs[l * 16 + n + 3] * h[n + 3];
        }
        out[base + (size_t)l * DI] = ((y0 + y1) + (y2 + y3)) + x_v * Dv;
        dt_v = dt_nx; x_v = x_nx;
    }
}

// ---------------------------------------------------------------------------
extern "C" void kernel_launch(void* const* d_in, const int* in_sizes, int n_in,
                              void* d_out, int out_size, void* d_ws, size_t ws_size,
                              hipStream_t stream) {
    const float* x     = (const float*)d_in[0];
    const float* Wx    = (const float*)d_in[1];
    const float* Wdt   = (const float*)d_in[2];
    const float* bdt   = (const float*)d_in[3];
    const float* A_log = (const float*)d_in[4];
    const float* Dp    = (const float*)d_in[5];
    float* out = (float*)d_out;

    // Pick NC=32 if workspace allows, else NC=16. ws_size is constant across
    // calls -> deterministic branch, graph-capture safe.
    const size_t xz_n = (size_t)NROW * KXZ;       // 655360
    const size_t dt_n = (size_t)NROW * DI;        // 8388608
    int ncshift = 5;
    {
        const size_t nc = 32;
        const size_t need = (xz_n + dt_n + B_ * nc * DI + 2 * B_ * nc * DS * DI) * 4;
        if (ws_size < need) ncshift = 4;
    }
    const int nc = 1 << ncshift;

    float* ws  = (float*)d_ws;
    float* xz  = ws;
    float* dt  = xz + xz_n;
    float* Sws = dt + dt_n;
    float* LE  = Sws + (size_t)B_ * nc * DI;
    float* H0  = LE + (size_t)B_ * nc * DS * DI;

    hipMemsetAsync(xz, 0, xz_n * sizeof(float), stream);
    k_gemm_xz<<<32 * XKS, 256, 0, stream>>>(x, Wx, xz);
    k_gemm_dt<<<64 * 16, 256, 0, stream>>>(xz, Wdt, bdt, dt);
    k_scan_a<<<B_ * nc * 8, 256, 0, stream>>>(dt, x, xz, A_log, Sws, LE, ncshift);
    k_scan_b<<<B_ * DI / 256, 256, 0, stream>>>(A_log, Sws, LE, H0, ncshift);
    k_scan_c<<<B_ * nc * 8, 256, 0, stream>>>(dt, x, xz, A_log, H0, Dp, out, ncshift);
}